// Round 14
// baseline (113.273 us; speedup 1.0000x reference)
//
#include <hip/hip_runtime.h>

// ManifoldCrossAttention on MI355X (gfx950), bf16 MFMA pipeline, f32 I/O.
//
// Round 14 = round 11 (best attn: 42us, direct loads, 128-thr/2-wave blocks)
// with ONE change: k_attn processes its chunks in PAIRS -- two fully
// independent QK->softmax->PV chains per iteration, interleaved so each
// stage of chain 0 hides under chain 1's latency (ILP attack on the ~800cyc
// serial chain that 8 structural variants proved invariant to TLP/traffic/
// staging fixes; VALUBusy 31% @ 3.4 waves/SIMD = dependency-bound).
// GEMMs/prep byte-identical to rounds 9-13.
//
// Fragment layouts (bf16 element offsets):
//  Wf [p][mt=8][ks=16][fr=4][lane=64][8]   : W[o=mt*64+fr*16+(l&15)][c=ks*32+(l>>4)*8+j]
//  Xf [b][ntw=27][ks=16][fc=4][lane][8]    : X[m=ntw*64+fc*16+(l&15)][c=ks*32+(l>>4)*8+j]
//  Qf/Kf [bh=32][ck=54][kf=4][lane][8]     : M[row=ck*32+(l&31)][d=kf*16+(l>>5)*8+j]
//     (Qf values pre-scaled by 0.18033688 = 0.125*log2(e))
//  Vf [bh][ck=54][dt=2][kf2=2][lane][8]    : V[d=dt*32+(l&31)][m=ck*32+kf2*16+(l>>5)*8+j]
//  Of -- same as Xf (consumed by k_gemm_out as B operand)
//
// Workspace: Wf@0 (2MB), Xf/Of@2097152 (7MB), Qf@9175040, Kf@16252928,
//            Vf@23330816 -- total 30408704 B.

using bf16x8 = __attribute__((ext_vector_type(8))) short;
using f32x4  = __attribute__((ext_vector_type(4))) float;
using f32x16 = __attribute__((ext_vector_type(16))) float;
using u32x4  = __attribute__((ext_vector_type(4))) unsigned int;
using u16x4  = __attribute__((ext_vector_type(4))) unsigned short;
using u16x8  = __attribute__((ext_vector_type(8))) unsigned short;

#define MFMA16(a, b, c) __builtin_amdgcn_mfma_f32_16x16x32_bf16((a), (b), (c), 0, 0, 0)
#define MFMA32(a, b, c) __builtin_amdgcn_mfma_f32_32x32x16_bf16((a), (b), (c), 0, 0, 0)

__device__ __forceinline__ unsigned short f2bf(float f) {
  unsigned int u = __float_as_uint(f);
  return (unsigned short)((u + 0x7fffu + ((u >> 16) & 1u)) >> 16);  // RNE
}

__device__ __forceinline__ f32x16 zero16() {
  f32x16 z;
#pragma unroll
  for (int i = 0; i < 16; ++i) z[i] = 0.f;
  return z;
}

// ------------------------------------------------- prep: weights cvt + X pack
__global__ __launch_bounds__(256) void k_prep(
    const float* __restrict__ Wq, const float* __restrict__ Wk,
    const float* __restrict__ Wv, const float* __restrict__ Wo,
    const float* __restrict__ f0, const float* __restrict__ f1,
    const float* __restrict__ f2,
    unsigned short* __restrict__ Wf, unsigned short* __restrict__ Xf) {
  __shared__ unsigned short tile[64][65];
  const int bid = blockIdx.x;
  const int t = threadIdx.x;
  if (bid < 1024) {
    int idx = (bid * 256 + t) * 4;
    int p   = idx >> 18;
    int rem = idx & 262143;
    int o = rem >> 9, c0 = rem & 511;
    const float* s = p == 0 ? Wq : p == 1 ? Wk : p == 2 ? Wv : Wo;
    f32x4 v = *(const f32x4*)(s + rem);
    u16x4 pk;
    pk[0] = f2bf(v[0]); pk[1] = f2bf(v[1]); pk[2] = f2bf(v[2]); pk[3] = f2bf(v[3]);
    int mt = o >> 6, fr = (o & 63) >> 4, lr = o & 15;
    int ks = c0 >> 5, lg = (c0 & 31) >> 3, j0 = c0 & 7;  // j0 in {0,4}
    size_t off = (size_t)((((p * 8 + mt) * 16 + ks) * 4 + fr)) * 512 +
                 (lg * 16 + lr) * 8 + j0;
    *(u16x4*)(Wf + off) = pk;
    return;
  }
  const int id = bid - 1024;
  const int nt = id % 9;                // n tile of 64
  const int ct = (id / 9) % 8;          // c tile of 64
  const int z  = id / 72;               // b*3+f
  const int b = z / 3, f = z % 3;
  const float* src = (f == 0 ? f0 : f == 1 ? f1 : f2) + b * (512 * 576);

#pragma unroll
  for (int i = 0; i < 16; ++i) {
    int idx = i * 256 + t;
    int cc = idx >> 6, nn = idx & 63;    // coalesced over nn
    tile[cc][nn] = f2bf(src[(ct * 64 + cc) * 576 + nt * 64 + nn]);
  }
  __syncthreads();
  const int ntw = f * 9 + nt;            // global m-tile (0..26)
#pragma unroll
  for (int i = 0; i < 4; ++i) {
    int slot = i * 256 + t;              // 1024 slots: [nn=64][cquad=16]
    int nn = slot >> 4, cq = slot & 15;
    int cl = cq * 4;                     // c_local
    int c  = ct * 64 + cl;
    int fc = nn >> 4, lr = nn & 15;
    int ks = c >> 5, lg = (c & 31) >> 3, j0 = c & 7;
    u16x4 pk;
    pk[0] = tile[cl][nn]; pk[1] = tile[cl + 1][nn];
    pk[2] = tile[cl + 2][nn]; pk[3] = tile[cl + 3][nn];
    size_t off = (size_t)((((b * 27 + ntw) * 16 + ks) * 4 + fc)) * 512 +
                 (lg * 16 + lr) * 8 + j0;
    *(u16x4*)(Xf + off) = pk;
  }
}

// ---------------------------------------------------------------- QKV GEMM
// 64x32 tiles per wave, 1296 blocks, XCD-remapped (b = xcd>>1, parity = xcd&1).
__global__ __launch_bounds__(256) void k_gemm_qkv(
    const unsigned short* __restrict__ Wf, const unsigned short* __restrict__ Xf,
    const float* __restrict__ bq, const float* __restrict__ bk,
    const float* __restrict__ bv,
    unsigned short* __restrict__ Qf, unsigned short* __restrict__ Kf,
    unsigned short* __restrict__ Vf) {
  const int id = blockIdx.x;                 // 0..1295
  const int xcd = id & 7, s = id >> 3;       // s: 0..161
  const int b = xcd >> 1, par = xcd & 1;
  const int p = s / 54, bx = (s % 54) * 2 + par;   // bx: 0..107
  const int t = threadIdx.x, w = t >> 6, l = t & 63, lg = l >> 4, lr = l & 15;
  const int wid = bx * 4 + w;                // 0..431 = 8 mt * 27 ntw * 2 half
  const int mt = wid / 54, rest = wid % 54;
  const int ntw = rest >> 1, half = rest & 1;
  const unsigned short* A = Wf + (size_t)(p * 8 + mt) * 16 * 2048 + l * 8;
  const unsigned short* B = Xf + (size_t)(b * 27 + ntw) * 16 * 2048 +
                            half * 1024 + l * 8;

  f32x4 acc[4][2];
#pragma unroll
  for (int fr = 0; fr < 4; ++fr)
#pragma unroll
    for (int fc = 0; fc < 2; ++fc) acc[fr][fc] = (f32x4){0.f, 0.f, 0.f, 0.f};

#pragma unroll 2
  for (int ks = 0; ks < 16; ++ks) {
    bf16x8 af[4], bfv[2];
#pragma unroll
    for (int fr = 0; fr < 4; ++fr)
      af[fr] = *(const bf16x8*)(A + ks * 2048 + fr * 512);
#pragma unroll
    for (int fc = 0; fc < 2; ++fc)
      bfv[fc] = *(const bf16x8*)(B + ks * 2048 + fc * 512);
#pragma unroll
    for (int fr = 0; fr < 4; ++fr)
#pragma unroll
      for (int fc = 0; fc < 2; ++fc)
        acc[fr][fc] = MFMA16(af[fr], bfv[fc], acc[fr][fc]);
  }

  const float* bias = p == 0 ? bq : p == 1 ? bk : bv;
  const int bh = b * 8 + mt;
  const int ck = ntw * 2 + half;             // per-wave constant KV chunk
#pragma unroll
  for (int fr = 0; fr < 4; ++fr) {
    f32x4 b4 = *(const f32x4*)(bias + mt * 64 + fr * 16 + lg * 4);
#pragma unroll
    for (int fc = 0; fc < 2; ++fc) {
      if (p < 2) {
        unsigned short* outF = (p == 0) ? Qf : Kf;
        u16x4 pk;
#pragma unroll
        for (int r = 0; r < 4; ++r) {
          float v = acc[fr][fc][r] + b4[r];
          if (p == 0) v *= 0.18033688f;      // fold softmax scale into Q
          pk[r] = f2bf(v);
        }
        size_t off = ((size_t)bh * 54 + ck) * 2048 + fr * 512 +
                     ((lg >> 1) * 32 + fc * 16 + lr) * 8 + (lg & 1) * 4;
        *(u16x4*)(outF + off) = pk;
      } else {
        size_t base = ((size_t)bh * 54 + ck) * 2048 +
                      ((fr >> 1) * 2 + fc) * 512 +
                      (((lr >> 3) & 1) * 32 + (fr & 1) * 16 + lg * 4) * 8 +
                      (lr & 7);
#pragma unroll
        for (int r = 0; r < 4; ++r)
          Vf[base + r * 8] = f2bf(acc[fr][fc][r] + b4[r]);
      }
    }
  }
}

// ---------------------------------------------------------------- attention
// 128-thread blocks (2 waves), 1 q-tile per block, waves split 54 KV chunks
// 2-way; chunks processed in PAIRS: two independent QK->softmax->PV chains
// interleaved per iteration (13 pairs + 1 tail). XCD-swizzled grid of 1728.
__device__ __forceinline__ void softmax_pa(const f32x16& s, float& lsum,
                                           bf16x8& pa0, bf16x8& pa1, int hi) {
  unsigned int W[8];
  float a0 = 0.f, a1 = 0.f;
#pragma unroll
  for (int u = 0; u < 8; ++u) {
    float e0, e1;
    asm("v_exp_f32 %0, %1" : "=v"(e0) : "v"(s[2 * u]));
    asm("v_exp_f32 %0, %1" : "=v"(e1) : "v"(s[2 * u + 1]));
    a0 += e0; a1 += e1;
    asm("v_cvt_pk_bf16_f32 %0, %1, %2" : "=v"(W[u]) : "v"(e0), "v"(e1));
  }
  lsum += a0 + a1;
  unsigned int fw[2][4];
#pragma unroll
  for (int kf = 0; kf < 2; ++kf)
#pragma unroll
    for (int wd = 0; wd < 2; ++wd) {
      unsigned int lo  = W[4 * kf + wd];
      unsigned int hw  = W[4 * kf + 2 + wd];
      unsigned int pub = hi ? lo : hw;
      unsigned int rcv = (unsigned int)__shfl_xor((int)pub, 32, 64);
      fw[kf][wd]     = hi ? rcv : lo;
      fw[kf][2 + wd] = hi ? hw : rcv;
    }
  u32x4 w0, w1;
  w0[0] = fw[0][0]; w0[1] = fw[0][1]; w0[2] = fw[0][2]; w0[3] = fw[0][3];
  w1[0] = fw[1][0]; w1[1] = fw[1][1]; w1[2] = fw[1][2]; w1[3] = fw[1][3];
  pa0 = __builtin_bit_cast(bf16x8, w0);
  pa1 = __builtin_bit_cast(bf16x8, w1);
}

__global__ __launch_bounds__(128, 3) void k_attn(
    const unsigned short* __restrict__ Qf, const unsigned short* __restrict__ Kf,
    const unsigned short* __restrict__ Vf, unsigned short* __restrict__ Of) {
  const int id = blockIdx.x;                 // 0..1727
  const int xcd = id & 7, slot = id >> 3;    // slot 0..215
  const int bh = xcd * 4 + (slot / 54);      // XCD k owns bh 4k..4k+3
  const int qt = slot % 54;                  // q-tile 0..53
  const int b = bh >> 3, h = bh & 7;
  const int t = threadIdx.x, w = t >> 6, l = t & 63;
  const int lr = l & 31, hi = l >> 5;

  __shared__ float Obuf[2][32][68];
  __shared__ float Lbuf[2][32];

  const unsigned short* Qb = Qf + ((size_t)bh * 54 + qt) * 2048 + l * 8;
  bf16x8 bq[4];
#pragma unroll
  for (int kf = 0; kf < 4; ++kf) bq[kf] = *(const bf16x8*)(Qb + kf * 512);

  f32x16 oacc[2];
  oacc[0] = zero16(); oacc[1] = zero16();
  float ls = 0.f;

  const unsigned short* Kb = Kf + (size_t)bh * 54 * 2048 + l * 8;
  const unsigned short* Vb = Vf + (size_t)bh * 54 * 2048 + l * 8;

  // paired main loop: chunks (ck, ck+2), 13 iterations
#pragma unroll 1
  for (int ck = w; ck < w + 52; ck += 4) {
    const unsigned short* kc0 = Kb + ck * 2048;
    const unsigned short* kc1 = Kb + (ck + 2) * 2048;
    bf16x8 ak0[4], ak1[4];
#pragma unroll
    for (int i = 0; i < 4; ++i) ak0[i] = *(const bf16x8*)(kc0 + i * 512);
#pragma unroll
    for (int i = 0; i < 4; ++i) ak1[i] = *(const bf16x8*)(kc1 + i * 512);

    f32x16 sA0 = zero16();
#pragma unroll
    for (int kf = 0; kf < 4; ++kf) sA0 = MFMA32(ak0[kf], bq[kf], sA0);

    bf16x8 vb0[4];
    const unsigned short* vc0 = Vb + ck * 2048;
#pragma unroll
    for (int i = 0; i < 4; ++i) vb0[i] = *(const bf16x8*)(vc0 + i * 512);

    f32x16 sA1 = zero16();
#pragma unroll
    for (int kf = 0; kf < 4; ++kf) sA1 = MFMA32(ak1[kf], bq[kf], sA1);

    bf16x8 vb1[4];
    const unsigned short* vc1 = Vb + (ck + 2) * 2048;
#pragma unroll
    for (int i = 0; i < 4; ++i) vb1[i] = *(const bf16x8*)(vc1 + i * 512);

    bf16x8 pa0, pa1;
    softmax_pa(sA0, ls, pa0, pa1, hi);       // chain0; QK1 in its shadow
    oacc[0] = MFMA32(pa0, vb0[0], oacc[0]);
    oacc[0] = MFMA32(pa1, vb0[1], oacc[0]);
    oacc[1] = MFMA32(pa0, vb0[2], oacc[1]);
    oacc[1] = MFMA32(pa1, vb0[3], oacc[1]);

    softmax_pa(sA1, ls, pa0, pa1, hi);       // chain1; PV0 in its shadow
    oacc[0] = MFMA32(pa0, vb1[0], oacc[0]);
    oacc[0] = MFMA32(pa1, vb1[1], oacc[0]);
    oacc[1] = MFMA32(pa0, vb1[2], oacc[1]);
    oacc[1] = MFMA32(pa1, vb1[3], oacc[1]);
  }

  // tail chunk: ck = w + 52
  {
    const int ck = w + 52;
    const unsigned short* kc = Kb + ck * 2048;
    const unsigned short* vc = Vb + ck * 2048;
    bf16x8 ak[4];
#pragma unroll
    for (int i = 0; i < 4; ++i) ak[i] = *(const bf16x8*)(kc + i * 512);
    f32x16 sA = zero16();
#pragma unroll
    for (int kf = 0; kf < 4; ++kf) sA = MFMA32(ak[kf], bq[kf], sA);
    bf16x8 vb[4];
#pragma unroll
    for (int i = 0; i < 4; ++i) vb[i] = *(const bf16x8*)(vc + i * 512);
    bf16x8 pa0, pa1;
    softmax_pa(sA, ls, pa0, pa1, hi);
    oacc[0] = MFMA32(pa0, vb[0], oacc[0]);
    oacc[0] = MFMA32(pa1, vb[1], oacc[0]);
    oacc[1] = MFMA32(pa0, vb[2], oacc[1]);
    oacc[1] = MFMA32(pa1, vb[3], oacc[1]);
  }

  // ---- epilogue: combine 2 waves via LDS, normalize, store Of
  float lt = ls + __shfl_xor(ls, 32, 64);
  if (l < 32) Lbuf[w][lr] = lt;
#pragma unroll
  for (int dt = 0; dt < 2; ++dt)
#pragma unroll
    for (int r = 0; r < 16; ++r)
      Obuf[w][(r & 3) + 8 * (r >> 2) + 4 * hi][dt * 32 + lr] = oacc[dt][r];
  __syncthreads();

  const int n = t >> 2, dq = t & 3;          // n 0..31, d-quarter 0..3
  float ltot = Lbuf[0][n] + Lbuf[1][n];
  float linv = 1.0f / ltot;
#pragma unroll
  for (int part = 0; part < 2; ++part) {
    const int d0 = dq * 16 + part * 8;
    u16x8 o8;
#pragma unroll
    for (int i = 0; i < 8; ++i) {
      float ov = Obuf[0][n][d0 + i] + Obuf[1][n][d0 + i];
      o8[i] = f2bf(ov * linv);
    }
    size_t off = (size_t)((((b * 27 + (qt >> 1)) * 16 + h * 2 + (d0 >> 5)) * 4 +
                           (qt & 1) * 2 + (n >> 4))) * 512 +
                 ((d0 >> 3) & 3) * 128 + (n & 15) * 8;
    *(u16x8*)(Of + off) = o8;
  }
}

// ---------------------------------------------------------------- out proj
// 64x32 tiles per wave, grid 36 x 12 (432 blocks).
__global__ __launch_bounds__(256) void k_gemm_out(
    const unsigned short* __restrict__ Wf, const unsigned short* __restrict__ Of,
    const float* __restrict__ bo,
    const float* __restrict__ f0, const float* __restrict__ f1,
    const float* __restrict__ f2, float* __restrict__ out) {
  const int z = blockIdx.z, b = z / 3, f = z % 3;
  const int t = threadIdx.x, w = t >> 6, l = t & 63, lg = l >> 4, lr = l & 15;
  const int wid = blockIdx.x * 4 + w;        // 0..143 = 8 mt * 9 ntw * 2 half
  const int mt = wid / 18, rest = wid % 18;
  const int ntw = rest >> 1, half = rest & 1;
  const int o0 = mt * 64;
  const unsigned short* A = Wf + (size_t)(3 * 8 + mt) * 16 * 2048 + l * 8;
  const unsigned short* B = Of + (size_t)(b * 27 + f * 9 + ntw) * 16 * 2048 +
                            half * 1024 + l * 8;

  f32x4 acc[4][2];
#pragma unroll
  for (int fr = 0; fr < 4; ++fr)
#pragma unroll
    for (int fc = 0; fc < 2; ++fc) acc[fr][fc] = (f32x4){0.f, 0.f, 0.f, 0.f};

#pragma unroll 2
  for (int ks = 0; ks < 16; ++ks) {
    bf16x8 af[4], bfv[2];
#pragma unroll
    for (int fr = 0; fr < 4; ++fr)
      af[fr] = *(const bf16x8*)(A + ks * 2048 + fr * 512);
#pragma unroll
    for (int fc = 0; fc < 2; ++fc)
      bfv[fc] = *(const bf16x8*)(B + ks * 2048 + fc * 512);
#pragma unroll
    for (int fr = 0; fr < 4; ++fr)
#pragma unroll
      for (int fc = 0; fc < 2; ++fc)
        acc[fr][fc] = MFMA16(af[fr], bfv[fc], acc[fr][fc]);
  }

  const float* ft = f == 0 ? f0 : f == 1 ? f1 : f2;
#pragma unroll
  for (int fr = 0; fr < 4; ++fr) {
    f32x4 b4 = *(const f32x4*)(bo + o0 + fr * 16 + lg * 4);
#pragma unroll
    for (int fc = 0; fc < 2; ++fc) {
      int ncol = ntw * 64 + half * 32 + fc * 16 + lr;
#pragma unroll
      for (int r = 0; r < 4; ++r) {
        int o = o0 + fr * 16 + lg * 4 + r;
        out[((f * 4 + b) * 512 + o) * 576 + ncol] =
            acc[fr][fc][r] + b4[r] + ft[(b * 512 + o) * 576 + ncol];
      }
    }
  }
}

// ---------------------------------------------------------------- launcher
extern "C" void kernel_launch(void* const* d_in, const int* in_sizes, int n_in,
                              void* d_out, int out_size, void* d_ws, size_t ws_size,
                              hipStream_t stream) {
  const float* f0 = (const float*)d_in[0];
  const float* f1 = (const float*)d_in[1];
  const float* f2 = (const float*)d_in[2];
  const float* Wq = (const float*)d_in[3];
  const float* bq = (const float*)d_in[4];
  const float* Wk = (const float*)d_in[5];
  const float* bk = (const float*)d_in[6];
  const float* Wv = (const float*)d_in[7];
  const float* bv = (const float*)d_in[8];
  const float* Wo = (const float*)d_in[9];
  const float* bo = (const float*)d_in[10];
  float* out = (float*)d_out;

  char* ws = (char*)d_ws;
  unsigned short* Wf = (unsigned short*)(ws);
  unsigned short* Xf = (unsigned short*)(ws + 2097152);
  unsigned short* Qf = (unsigned short*)(ws + 9175040);
  unsigned short* Kf = (unsigned short*)(ws + 16252928);
  unsigned short* Vf = (unsigned short*)(ws + 23330816);
  unsigned short* Of = Xf;  // Xf dead after k_gemm_qkv; reused for attention out

  k_prep<<<dim3(1888), 256, 0, stream>>>(Wq, Wk, Wv, Wo, f0, f1, f2, Wf, Xf);
  k_gemm_qkv<<<dim3(1296), 256, 0, stream>>>(Wf, Xf, bq, bk, bv, Qf, Kf, Vf);
  k_attn<<<dim3(1728), 128, 0, stream>>>(Qf, Kf, Vf, Of);
  k_gemm_out<<<dim3(36, 1, 12), 256, 0, stream>>>(Wf, Of, bo, f0, f1, f2, out);
}

// Round 15
// 91.541 us; speedup vs baseline: 1.2374x; 1.2374x over previous
//
#include <hip/hip_runtime.h>

// ManifoldCrossAttention on MI355X (gfx950), bf16 MFMA pipeline, f32 I/O.
//
// Round 15 = round 11 attn/prep (attn 42us verified; r14 ILP attempt spilled
// and is reverted) + both GEMMs retiled 64x32 -> 32x32 per wave:
//   k_gemm_qkv: 2592 blocks, 10368 waves (10.1/SIMD launched, ~55 VGPR ->
//               8/SIMD resident tier; was 5.1/SIMD).
//   k_gemm_out: 864 blocks, 3456 waves (3.4/SIMD; was 1.69).
// Wave-count is the one lever that consistently paid (r9); both GEMMs are
// latency-bound with the same profile as attn.
//
// Fragment layouts (bf16 element offsets):
//  Wf [p][mt=8][ks=16][fr=4][lane=64][8]   : W[o=mt*64+fr*16+(l&15)][c=ks*32+(l>>4)*8+j]
//  Xf [b][ntw=27][ks=16][fc=4][lane][8]    : X[m=ntw*64+fc*16+(l&15)][c=ks*32+(l>>4)*8+j]
//  Qf/Kf [bh=32][ck=54][kf=4][lane][8]     : M[row=ck*32+(l&31)][d=kf*16+(l>>5)*8+j]
//     (Qf values pre-scaled by 0.18033688 = 0.125*log2(e))
//  Vf [bh][ck=54][dt=2][kf2=2][lane][8]    : V[d=dt*32+(l&31)][m=ck*32+kf2*16+(l>>5)*8+j]
//  Of -- same as Xf (consumed by k_gemm_out as B operand)
//
// Workspace: Wf@0 (2MB), Xf/Of@2097152 (7MB), Qf@9175040, Kf@16252928,
//            Vf@23330816 -- total 30408704 B.

using bf16x8 = __attribute__((ext_vector_type(8))) short;
using f32x4  = __attribute__((ext_vector_type(4))) float;
using f32x16 = __attribute__((ext_vector_type(16))) float;
using u32x4  = __attribute__((ext_vector_type(4))) unsigned int;
using u16x4  = __attribute__((ext_vector_type(4))) unsigned short;
using u16x8  = __attribute__((ext_vector_type(8))) unsigned short;

#define MFMA16(a, b, c) __builtin_amdgcn_mfma_f32_16x16x32_bf16((a), (b), (c), 0, 0, 0)
#define MFMA32(a, b, c) __builtin_amdgcn_mfma_f32_32x32x16_bf16((a), (b), (c), 0, 0, 0)

__device__ __forceinline__ unsigned short f2bf(float f) {
  unsigned int u = __float_as_uint(f);
  return (unsigned short)((u + 0x7fffu + ((u >> 16) & 1u)) >> 16);  // RNE
}

__device__ __forceinline__ f32x16 zero16() {
  f32x16 z;
#pragma unroll
  for (int i = 0; i < 16; ++i) z[i] = 0.f;
  return z;
}

// ------------------------------------------------- prep: weights cvt + X pack
__global__ __launch_bounds__(256) void k_prep(
    const float* __restrict__ Wq, const float* __restrict__ Wk,
    const float* __restrict__ Wv, const float* __restrict__ Wo,
    const float* __restrict__ f0, const float* __restrict__ f1,
    const float* __restrict__ f2,
    unsigned short* __restrict__ Wf, unsigned short* __restrict__ Xf) {
  __shared__ unsigned short tile[64][65];
  const int bid = blockIdx.x;
  const int t = threadIdx.x;
  if (bid < 1024) {
    int idx = (bid * 256 + t) * 4;
    int p   = idx >> 18;
    int rem = idx & 262143;
    int o = rem >> 9, c0 = rem & 511;
    const float* s = p == 0 ? Wq : p == 1 ? Wk : p == 2 ? Wv : Wo;
    f32x4 v = *(const f32x4*)(s + rem);
    u16x4 pk;
    pk[0] = f2bf(v[0]); pk[1] = f2bf(v[1]); pk[2] = f2bf(v[2]); pk[3] = f2bf(v[3]);
    int mt = o >> 6, fr = (o & 63) >> 4, lr = o & 15;
    int ks = c0 >> 5, lg = (c0 & 31) >> 3, j0 = c0 & 7;  // j0 in {0,4}
    size_t off = (size_t)((((p * 8 + mt) * 16 + ks) * 4 + fr)) * 512 +
                 (lg * 16 + lr) * 8 + j0;
    *(u16x4*)(Wf + off) = pk;
    return;
  }
  const int id = bid - 1024;
  const int nt = id % 9;                // n tile of 64
  const int ct = (id / 9) % 8;          // c tile of 64
  const int z  = id / 72;               // b*3+f
  const int b = z / 3, f = z % 3;
  const float* src = (f == 0 ? f0 : f == 1 ? f1 : f2) + b * (512 * 576);

#pragma unroll
  for (int i = 0; i < 16; ++i) {
    int idx = i * 256 + t;
    int cc = idx >> 6, nn = idx & 63;    // coalesced over nn
    tile[cc][nn] = f2bf(src[(ct * 64 + cc) * 576 + nt * 64 + nn]);
  }
  __syncthreads();
  const int ntw = f * 9 + nt;            // global m-tile (0..26)
#pragma unroll
  for (int i = 0; i < 4; ++i) {
    int slot = i * 256 + t;              // 1024 slots: [nn=64][cquad=16]
    int nn = slot >> 4, cq = slot & 15;
    int cl = cq * 4;                     // c_local
    int c  = ct * 64 + cl;
    int fc = nn >> 4, lr = nn & 15;
    int ks = c >> 5, lg = (c & 31) >> 3, j0 = c & 7;
    u16x4 pk;
    pk[0] = tile[cl][nn]; pk[1] = tile[cl + 1][nn];
    pk[2] = tile[cl + 2][nn]; pk[3] = tile[cl + 3][nn];
    size_t off = (size_t)((((b * 27 + ntw) * 16 + ks) * 4 + fc)) * 512 +
                 (lg * 16 + lr) * 8 + j0;
    *(u16x4*)(Xf + off) = pk;
  }
}

// ---------------------------------------------------------------- QKV GEMM
// 32x32 tiles per wave: 2592 blocks, XCD-remapped (b = xcd>>1, parity=xcd&1).
// wid in [0,864) = 16 mt32 * 54 nt32 per (b,p).
__global__ __launch_bounds__(256) void k_gemm_qkv(
    const unsigned short* __restrict__ Wf, const unsigned short* __restrict__ Xf,
    const float* __restrict__ bq, const float* __restrict__ bk,
    const float* __restrict__ bv,
    unsigned short* __restrict__ Qf, unsigned short* __restrict__ Kf,
    unsigned short* __restrict__ Vf) {
  const int id = blockIdx.x;                 // 0..2591
  const int xcd = id & 7, s = id >> 3;       // s: 0..323
  const int b = xcd >> 1, par = xcd & 1;
  const int p = s / 108, bx = (s % 108) * 2 + par;   // bx: 0..215
  const int t = threadIdx.x, w = t >> 6, l = t & 63, lg = l >> 4, lr = l & 15;
  const int wid = bx * 4 + w;                // 0..863 = 16 mt32 * 54 nt32
  const int mt32 = wid / 54, nt32 = wid % 54;
  const unsigned short* A = Wf + (size_t)(p * 8 + (mt32 >> 1)) * 16 * 2048 +
                            (mt32 & 1) * 1024 + l * 8;
  const unsigned short* B = Xf + (size_t)(b * 27 + (nt32 >> 1)) * 16 * 2048 +
                            (nt32 & 1) * 1024 + l * 8;

  f32x4 acc[2][2];
#pragma unroll
  for (int fr = 0; fr < 2; ++fr)
#pragma unroll
    for (int fc = 0; fc < 2; ++fc) acc[fr][fc] = (f32x4){0.f, 0.f, 0.f, 0.f};

#pragma unroll 2
  for (int ks = 0; ks < 16; ++ks) {
    bf16x8 af[2], bfv[2];
#pragma unroll
    for (int fr = 0; fr < 2; ++fr)
      af[fr] = *(const bf16x8*)(A + ks * 2048 + fr * 512);
#pragma unroll
    for (int fc = 0; fc < 2; ++fc)
      bfv[fc] = *(const bf16x8*)(B + ks * 2048 + fc * 512);
#pragma unroll
    for (int fr = 0; fr < 2; ++fr)
#pragma unroll
      for (int fc = 0; fc < 2; ++fc)
        acc[fr][fc] = MFMA16(af[fr], bfv[fc], acc[fr][fc]);
  }

  const float* bias = p == 0 ? bq : p == 1 ? bk : bv;
  const int bh = b * 8 + (mt32 >> 1);        // head = mt32>>1
  const int ck = nt32;                       // n-tile of 32 == KV chunk
#pragma unroll
  for (int fr = 0; fr < 2; ++fr) {
    // o = mt32*32 + fr*16 + lg*4 + r ; d = o&63 = (mt32&1)*32 + fr*16 + lg*4 + r
    f32x4 b4 = *(const f32x4*)(bias + mt32 * 32 + fr * 16 + lg * 4);
#pragma unroll
    for (int fc = 0; fc < 2; ++fc) {
      if (p < 2) {
        // kf = (mt32&1)*2 + fr ; rowslot = fc*16 + lr ; hi_d = lg>>1 ; j0=(lg&1)*4
        unsigned short* outF = (p == 0) ? Qf : Kf;
        u16x4 pk;
#pragma unroll
        for (int r = 0; r < 4; ++r) {
          float v = acc[fr][fc][r] + b4[r];
          if (p == 0) v *= 0.18033688f;      // fold softmax scale into Q
          pk[r] = f2bf(v);
        }
        size_t off = ((size_t)bh * 54 + ck) * 2048 +
                     ((mt32 & 1) * 2 + fr) * 512 +
                     ((lg >> 1) * 32 + fc * 16 + lr) * 8 + (lg & 1) * 4;
        *(u16x4*)(outF + off) = pk;
      } else {
        // V: dt = mt32&1 ; dlane = fr*16+lg*4+r ; kf2 = fc ; hi_m = lr>>3 ; j = lr&7
        size_t base = ((size_t)bh * 54 + ck) * 2048 +
                      ((mt32 & 1) * 2 + fc) * 512 +
                      ((lr >> 3) * 32 + fr * 16 + lg * 4) * 8 +
                      (lr & 7);
#pragma unroll
        for (int r = 0; r < 4; ++r)
          Vf[base + r * 8] = f2bf(acc[fr][fc][r] + b4[r]);
      }
    }
  }
}

// ---------------------------------------------------------------- attention
// (round-11 verified, byte-identical) 128-thread blocks (2 waves), 1 q-tile
// per block, waves split 54 KV chunks 2-way. XCD-swizzled grid of 1728.
__device__ __forceinline__ void softmax_pa(const f32x16& s, float& lsum,
                                           bf16x8& pa0, bf16x8& pa1, int hi) {
  unsigned int W[8];
  float a0 = 0.f, a1 = 0.f;
#pragma unroll
  for (int u = 0; u < 8; ++u) {
    float e0, e1;
    asm("v_exp_f32 %0, %1" : "=v"(e0) : "v"(s[2 * u]));
    asm("v_exp_f32 %0, %1" : "=v"(e1) : "v"(s[2 * u + 1]));
    a0 += e0; a1 += e1;
    asm("v_cvt_pk_bf16_f32 %0, %1, %2" : "=v"(W[u]) : "v"(e0), "v"(e1));
  }
  lsum += a0 + a1;
  unsigned int fw[2][4];
#pragma unroll
  for (int kf = 0; kf < 2; ++kf)
#pragma unroll
    for (int wd = 0; wd < 2; ++wd) {
      unsigned int lo  = W[4 * kf + wd];
      unsigned int hw  = W[4 * kf + 2 + wd];
      unsigned int pub = hi ? lo : hw;
      unsigned int rcv = (unsigned int)__shfl_xor((int)pub, 32, 64);
      fw[kf][wd]     = hi ? rcv : lo;
      fw[kf][2 + wd] = hi ? hw : rcv;
    }
  u32x4 w0, w1;
  w0[0] = fw[0][0]; w0[1] = fw[0][1]; w0[2] = fw[0][2]; w0[3] = fw[0][3];
  w1[0] = fw[1][0]; w1[1] = fw[1][1]; w1[2] = fw[1][2]; w1[3] = fw[1][3];
  pa0 = __builtin_bit_cast(bf16x8, w0);
  pa1 = __builtin_bit_cast(bf16x8, w1);
}

__global__ __launch_bounds__(128, 4) void k_attn(
    const unsigned short* __restrict__ Qf, const unsigned short* __restrict__ Kf,
    const unsigned short* __restrict__ Vf, unsigned short* __restrict__ Of) {
  const int id = blockIdx.x;                 // 0..1727
  const int xcd = id & 7, slot = id >> 3;    // slot 0..215
  const int bh = xcd * 4 + (slot / 54);      // XCD k owns bh 4k..4k+3
  const int qt = slot % 54;                  // q-tile 0..53
  const int b = bh >> 3, h = bh & 7;
  const int t = threadIdx.x, w = t >> 6, l = t & 63;
  const int lr = l & 31, hi = l >> 5;

  __shared__ float Obuf[2][32][68];
  __shared__ float Lbuf[2][32];

  const unsigned short* Qb = Qf + ((size_t)bh * 54 + qt) * 2048 + l * 8;
  bf16x8 bq[4];
#pragma unroll
  for (int kf = 0; kf < 4; ++kf) bq[kf] = *(const bf16x8*)(Qb + kf * 512);

  f32x16 oacc[2];
  oacc[0] = zero16(); oacc[1] = zero16();
  float ls = 0.f;

  const unsigned short* Kb = Kf + (size_t)bh * 54 * 2048 + l * 8;
  const unsigned short* Vb = Vf + (size_t)bh * 54 * 2048 + l * 8;

#pragma unroll 1
  for (int ck = w; ck < 54; ck += 2) {
    const unsigned short* kc = Kb + ck * 2048;
    const unsigned short* vc = Vb + ck * 2048;
    bf16x8 ak[4];
#pragma unroll
    for (int i = 0; i < 4; ++i) ak[i] = *(const bf16x8*)(kc + i * 512);

    f32x16 sA = zero16();
#pragma unroll
    for (int kf = 0; kf < 4; ++kf) sA = MFMA32(ak[kf], bq[kf], sA);

    // V issued after QK (registers reuse ak's slots; latency covered by
    // the softmax below).
    bf16x8 vb[4];
#pragma unroll
    for (int i = 0; i < 4; ++i) vb[i] = *(const bf16x8*)(vc + i * 512);

    bf16x8 pa0, pa1;
    softmax_pa(sA, ls, pa0, pa1, hi);

    oacc[0] = MFMA32(pa0, vb[0], oacc[0]);
    oacc[0] = MFMA32(pa1, vb[1], oacc[0]);
    oacc[1] = MFMA32(pa0, vb[2], oacc[1]);
    oacc[1] = MFMA32(pa1, vb[3], oacc[1]);
  }

  // ---- epilogue: combine 2 waves via LDS, normalize, store Of
  float lt = ls + __shfl_xor(ls, 32, 64);
  if (l < 32) Lbuf[w][lr] = lt;
#pragma unroll
  for (int dt = 0; dt < 2; ++dt)
#pragma unroll
    for (int r = 0; r < 16; ++r)
      Obuf[w][(r & 3) + 8 * (r >> 2) + 4 * hi][dt * 32 + lr] = oacc[dt][r];
  __syncthreads();

  const int n = t >> 2, dq = t & 3;          // n 0..31, d-quarter 0..3
  float ltot = Lbuf[0][n] + Lbuf[1][n];
  float linv = 1.0f / ltot;
#pragma unroll
  for (int part = 0; part < 2; ++part) {
    const int d0 = dq * 16 + part * 8;
    u16x8 o8;
#pragma unroll
    for (int i = 0; i < 8; ++i) {
      float ov = Obuf[0][n][d0 + i] + Obuf[1][n][d0 + i];
      o8[i] = f2bf(ov * linv);
    }
    size_t off = (size_t)((((b * 27 + (qt >> 1)) * 16 + h * 2 + (d0 >> 5)) * 4 +
                           (qt & 1) * 2 + (n >> 4))) * 512 +
                 ((d0 >> 3) & 3) * 128 + (n & 15) * 8;
    *(u16x8*)(Of + off) = o8;
  }
}

// ---------------------------------------------------------------- out proj
// 32x32 tiles per wave: 864 blocks (72 x 12). wid in [0,288) = 16 mt32 * 18 nt32.
__global__ __launch_bounds__(256) void k_gemm_out(
    const unsigned short* __restrict__ Wf, const unsigned short* __restrict__ Of,
    const float* __restrict__ bo,
    const float* __restrict__ f0, const float* __restrict__ f1,
    const float* __restrict__ f2, float* __restrict__ out) {
  const int z = blockIdx.z, b = z / 3, f = z % 3;
  const int t = threadIdx.x, w = t >> 6, l = t & 63, lg = l >> 4, lr = l & 15;
  const int wid = blockIdx.x * 4 + w;        // 0..287
  const int mt32 = wid / 18, nt32 = wid % 18;
  const unsigned short* A = Wf + (size_t)(3 * 8 + (mt32 >> 1)) * 16 * 2048 +
                            (mt32 & 1) * 1024 + l * 8;
  const unsigned short* B = Of + (size_t)(b * 27 + f * 9 + (nt32 >> 1)) * 16 * 2048 +
                            (nt32 & 1) * 1024 + l * 8;

  f32x4 acc[2][2];
#pragma unroll
  for (int fr = 0; fr < 2; ++fr)
#pragma unroll
    for (int fc = 0; fc < 2; ++fc) acc[fr][fc] = (f32x4){0.f, 0.f, 0.f, 0.f};

#pragma unroll 2
  for (int ks = 0; ks < 16; ++ks) {
    bf16x8 af[2], bfv[2];
#pragma unroll
    for (int fr = 0; fr < 2; ++fr)
      af[fr] = *(const bf16x8*)(A + ks * 2048 + fr * 512);
#pragma unroll
    for (int fc = 0; fc < 2; ++fc)
      bfv[fc] = *(const bf16x8*)(B + ks * 2048 + fc * 512);
#pragma unroll
    for (int fr = 0; fr < 2; ++fr)
#pragma unroll
      for (int fc = 0; fc < 2; ++fc)
        acc[fr][fc] = MFMA16(af[fr], bfv[fc], acc[fr][fc]);
  }

  const float* ft = f == 0 ? f0 : f == 1 ? f1 : f2;
#pragma unroll
  for (int fr = 0; fr < 2; ++fr) {
    f32x4 b4 = *(const f32x4*)(bo + mt32 * 32 + fr * 16 + lg * 4);
#pragma unroll
    for (int fc = 0; fc < 2; ++fc) {
      int ncol = nt32 * 32 + fc * 16 + lr;
#pragma unroll
      for (int r = 0; r < 4; ++r) {
        int o = mt32 * 32 + fr * 16 + lg * 4 + r;
        out[((f * 4 + b) * 512 + o) * 576 + ncol] =
            acc[fr][fc][r] + b4[r] + ft[(b * 512 + o) * 576 + ncol];
      }
    }
  }
}

// ---------------------------------------------------------------- launcher
extern "C" void kernel_launch(void* const* d_in, const int* in_sizes, int n_in,
                              void* d_out, int out_size, void* d_ws, size_t ws_size,
                              hipStream_t stream) {
  const float* f0 = (const float*)d_in[0];
  const float* f1 = (const float*)d_in[1];
  const float* f2 = (const float*)d_in[2];
  const float* Wq = (const float*)d_in[3];
  const float* bq = (const float*)d_in[4];
  const float* Wk = (const float*)d_in[5];
  const float* bk = (const float*)d_in[6];
  const float* Wv = (const float*)d_in[7];
  const float* bv = (const float*)d_in[8];
  const float* Wo = (const float*)d_in[9];
  const float* bo = (const float*)d_in[10];
  float* out = (float*)d_out;

  char* ws = (char*)d_ws;
  unsigned short* Wf = (unsigned short*)(ws);
  unsigned short* Xf = (unsigned short*)(ws + 2097152);
  unsigned short* Qf = (unsigned short*)(ws + 9175040);
  unsigned short* Kf = (unsigned short*)(ws + 16252928);
  unsigned short* Vf = (unsigned short*)(ws + 23330816);
  unsigned short* Of = Xf;  // Xf dead after k_gemm_qkv; reused for attention out

  k_prep<<<dim3(1888), 256, 0, stream>>>(Wq, Wk, Wv, Wo, f0, f1, f2, Wf, Xf);
  k_gemm_qkv<<<dim3(2592), 256, 0, stream>>>(Wf, Xf, bq, bk, bv, Qf, Kf, Vf);
  k_attn<<<dim3(1728), 128, 0, stream>>>(Qf, Kf, Vf, Of);
  k_gemm_out<<<dim3(72, 1, 12), 256, 0, stream>>>(Wf, Of, bo, f0, f1, f2, out);
}

// Round 16
// 90.599 us; speedup vs baseline: 1.2503x; 1.0104x over previous
//
#include <hip/hip_runtime.h>

// ManifoldCrossAttention on MI355X (gfx950), bf16 MFMA pipeline, f32 I/O.
//
// Round 16 = round 15 with ONE isolated change: sigma-permuted V layout.
// The PV A-operand's k-slot s inherently holds P[m=sigma(s)] (D-row map
// (r&3)+8(r>>2)+4hi vs A-k map 8hi+j); storing V row m at slot sigma(m)
// (sigma = swap bit2<->bit3, involution) makes the cvt_pk output words feed
// the PV MFMA directly -- deletes 4 serial ds-pipe shfl_xor + 12 cndmask
// from the ~1400cyc per-chunk chain. (The passing shuffle path provably
// builds the identity layout, so sigma-V is algebraically equivalent.
// Round 4's bundled attempt failed unexplained; this isolates it.)
//
// Fragment layouts (bf16 element offsets):
//  Wf [p][mt=8][ks=16][fr=4][lane=64][8]   : W[o=mt*64+fr*16+(l&15)][c=ks*32+(l>>4)*8+j]
//  Xf [b][ntw=27][ks=16][fc=4][lane][8]    : X[m=ntw*64+fc*16+(l&15)][c=ks*32+(l>>4)*8+j]
//  Qf/Kf [bh=32][ck=54][kf=4][lane][8]     : M[row=ck*32+(l&31)][d=kf*16+(l>>5)*8+j]
//     (Qf values pre-scaled by 0.18033688 = 0.125*log2(e))
//  Vf [bh][ck=54][dt=2][kf2=2][lane][8]    : V[d=dt*32+(l&31)][m=ck*32+kf2*16+sigma((l>>5)*8+j)]
//  Of -- same as Xf (consumed by k_gemm_out as B operand)
//
// Workspace: Wf@0 (2MB), Xf/Of@2097152 (7MB), Qf@9175040, Kf@16252928,
//            Vf@23330816 -- total 30408704 B.

using bf16x8 = __attribute__((ext_vector_type(8))) short;
using f32x4  = __attribute__((ext_vector_type(4))) float;
using f32x16 = __attribute__((ext_vector_type(16))) float;
using u32x4  = __attribute__((ext_vector_type(4))) unsigned int;
using u16x4  = __attribute__((ext_vector_type(4))) unsigned short;
using u16x8  = __attribute__((ext_vector_type(8))) unsigned short;

#define MFMA16(a, b, c) __builtin_amdgcn_mfma_f32_16x16x32_bf16((a), (b), (c), 0, 0, 0)
#define MFMA32(a, b, c) __builtin_amdgcn_mfma_f32_32x32x16_bf16((a), (b), (c), 0, 0, 0)

__device__ __forceinline__ unsigned short f2bf(float f) {
  unsigned int u = __float_as_uint(f);
  return (unsigned short)((u + 0x7fffu + ((u >> 16) & 1u)) >> 16);  // RNE
}

__device__ __forceinline__ f32x16 zero16() {
  f32x16 z;
#pragma unroll
  for (int i = 0; i < 16; ++i) z[i] = 0.f;
  return z;
}

// ------------------------------------------------- prep: weights cvt + X pack
__global__ __launch_bounds__(256) void k_prep(
    const float* __restrict__ Wq, const float* __restrict__ Wk,
    const float* __restrict__ Wv, const float* __restrict__ Wo,
    const float* __restrict__ f0, const float* __restrict__ f1,
    const float* __restrict__ f2,
    unsigned short* __restrict__ Wf, unsigned short* __restrict__ Xf) {
  __shared__ unsigned short tile[64][65];
  const int bid = blockIdx.x;
  const int t = threadIdx.x;
  if (bid < 1024) {
    int idx = (bid * 256 + t) * 4;
    int p   = idx >> 18;
    int rem = idx & 262143;
    int o = rem >> 9, c0 = rem & 511;
    const float* s = p == 0 ? Wq : p == 1 ? Wk : p == 2 ? Wv : Wo;
    f32x4 v = *(const f32x4*)(s + rem);
    u16x4 pk;
    pk[0] = f2bf(v[0]); pk[1] = f2bf(v[1]); pk[2] = f2bf(v[2]); pk[3] = f2bf(v[3]);
    int mt = o >> 6, fr = (o & 63) >> 4, lr = o & 15;
    int ks = c0 >> 5, lg = (c0 & 31) >> 3, j0 = c0 & 7;  // j0 in {0,4}
    size_t off = (size_t)((((p * 8 + mt) * 16 + ks) * 4 + fr)) * 512 +
                 (lg * 16 + lr) * 8 + j0;
    *(u16x4*)(Wf + off) = pk;
    return;
  }
  const int id = bid - 1024;
  const int nt = id % 9;                // n tile of 64
  const int ct = (id / 9) % 8;          // c tile of 64
  const int z  = id / 72;               // b*3+f
  const int b = z / 3, f = z % 3;
  const float* src = (f == 0 ? f0 : f == 1 ? f1 : f2) + b * (512 * 576);

#pragma unroll
  for (int i = 0; i < 16; ++i) {
    int idx = i * 256 + t;
    int cc = idx >> 6, nn = idx & 63;    // coalesced over nn
    tile[cc][nn] = f2bf(src[(ct * 64 + cc) * 576 + nt * 64 + nn]);
  }
  __syncthreads();
  const int ntw = f * 9 + nt;            // global m-tile (0..26)
#pragma unroll
  for (int i = 0; i < 4; ++i) {
    int slot = i * 256 + t;              // 1024 slots: [nn=64][cquad=16]
    int nn = slot >> 4, cq = slot & 15;
    int cl = cq * 4;                     // c_local
    int c  = ct * 64 + cl;
    int fc = nn >> 4, lr = nn & 15;
    int ks = c >> 5, lg = (c & 31) >> 3, j0 = c & 7;
    u16x4 pk;
    pk[0] = tile[cl][nn]; pk[1] = tile[cl + 1][nn];
    pk[2] = tile[cl + 2][nn]; pk[3] = tile[cl + 3][nn];
    size_t off = (size_t)((((b * 27 + ntw) * 16 + ks) * 4 + fc)) * 512 +
                 (lg * 16 + lr) * 8 + j0;
    *(u16x4*)(Xf + off) = pk;
  }
}

// ---------------------------------------------------------------- QKV GEMM
// 32x32 tiles per wave: 2592 blocks, XCD-remapped (b = xcd>>1, parity=xcd&1).
__global__ __launch_bounds__(256) void k_gemm_qkv(
    const unsigned short* __restrict__ Wf, const unsigned short* __restrict__ Xf,
    const float* __restrict__ bq, const float* __restrict__ bk,
    const float* __restrict__ bv,
    unsigned short* __restrict__ Qf, unsigned short* __restrict__ Kf,
    unsigned short* __restrict__ Vf) {
  const int id = blockIdx.x;                 // 0..2591
  const int xcd = id & 7, s = id >> 3;       // s: 0..323
  const int b = xcd >> 1, par = xcd & 1;
  const int p = s / 108, bx = (s % 108) * 2 + par;   // bx: 0..215
  const int t = threadIdx.x, w = t >> 6, l = t & 63, lg = l >> 4, lr = l & 15;
  const int wid = bx * 4 + w;                // 0..863 = 16 mt32 * 54 nt32
  const int mt32 = wid / 54, nt32 = wid % 54;
  const unsigned short* A = Wf + (size_t)(p * 8 + (mt32 >> 1)) * 16 * 2048 +
                            (mt32 & 1) * 1024 + l * 8;
  const unsigned short* B = Xf + (size_t)(b * 27 + (nt32 >> 1)) * 16 * 2048 +
                            (nt32 & 1) * 1024 + l * 8;

  f32x4 acc[2][2];
#pragma unroll
  for (int fr = 0; fr < 2; ++fr)
#pragma unroll
    for (int fc = 0; fc < 2; ++fc) acc[fr][fc] = (f32x4){0.f, 0.f, 0.f, 0.f};

#pragma unroll 2
  for (int ks = 0; ks < 16; ++ks) {
    bf16x8 af[2], bfv[2];
#pragma unroll
    for (int fr = 0; fr < 2; ++fr)
      af[fr] = *(const bf16x8*)(A + ks * 2048 + fr * 512);
#pragma unroll
    for (int fc = 0; fc < 2; ++fc)
      bfv[fc] = *(const bf16x8*)(B + ks * 2048 + fc * 512);
#pragma unroll
    for (int fr = 0; fr < 2; ++fr)
#pragma unroll
      for (int fc = 0; fc < 2; ++fc)
        acc[fr][fc] = MFMA16(af[fr], bfv[fc], acc[fr][fc]);
  }

  const float* bias = p == 0 ? bq : p == 1 ? bk : bv;
  const int bh = b * 8 + (mt32 >> 1);        // head = mt32>>1
  const int ck = nt32;                       // n-tile of 32 == KV chunk
#pragma unroll
  for (int fr = 0; fr < 2; ++fr) {
    f32x4 b4 = *(const f32x4*)(bias + mt32 * 32 + fr * 16 + lg * 4);
#pragma unroll
    for (int fc = 0; fc < 2; ++fc) {
      if (p < 2) {
        unsigned short* outF = (p == 0) ? Qf : Kf;
        u16x4 pk;
#pragma unroll
        for (int r = 0; r < 4; ++r) {
          float v = acc[fr][fc][r] + b4[r];
          if (p == 0) v *= 0.18033688f;      // fold softmax scale into Q
          pk[r] = f2bf(v);
        }
        size_t off = ((size_t)bh * 54 + ck) * 2048 +
                     ((mt32 & 1) * 2 + fr) * 512 +
                     ((lg >> 1) * 32 + fc * 16 + lr) * 8 + (lg & 1) * 4;
        *(u16x4*)(outF + off) = pk;
      } else {
        // V with sigma-permuted m-slot: m_local16 = lr stored at slot
        // x = sigma(lr) = swap bit2<->bit3 (so PV A-operand = cvt_pk words).
        int x = (lr & 3) | ((lr & 4) << 1) | ((lr & 8) >> 1);
        size_t base = ((size_t)bh * 54 + ck) * 2048 +
                      ((mt32 & 1) * 2 + fc) * 512 +
                      ((x >> 3) * 32 + fr * 16 + lg * 4) * 8 +
                      (x & 7);
#pragma unroll
        for (int r = 0; r < 4; ++r)
          Vf[base + r * 8] = f2bf(acc[fr][fc][r] + b4[r]);
      }
    }
  }
}

// ---------------------------------------------------------------- attention
// 128-thread blocks (2 waves), 1 q-tile per block, waves split 54 KV chunks
// 2-way. XCD-swizzled grid of 1728. Swapped QK^T (mfma32); softmax = bare
// v_exp (Q pre-scaled); sigma-V makes the PV A-operand = cvt_pk words
// directly (no cross-lane exchange in the main loop at all).
__device__ __forceinline__ void softmax_pa(const f32x16& s, float& lsum,
                                           bf16x8& pa0, bf16x8& pa1) {
  unsigned int W[8];
  float a0 = 0.f, a1 = 0.f;
#pragma unroll
  for (int u = 0; u < 8; ++u) {
    float e0, e1;
    asm("v_exp_f32 %0, %1" : "=v"(e0) : "v"(s[2 * u]));
    asm("v_exp_f32 %0, %1" : "=v"(e1) : "v"(s[2 * u + 1]));
    a0 += e0; a1 += e1;
    asm("v_cvt_pk_bf16_f32 %0, %1, %2" : "=v"(W[u]) : "v"(e0), "v"(e1));
  }
  lsum += a0 + a1;
  u32x4 w0, w1;
  w0[0] = W[0]; w0[1] = W[1]; w0[2] = W[2]; w0[3] = W[3];
  w1[0] = W[4]; w1[1] = W[5]; w1[2] = W[6]; w1[3] = W[7];
  pa0 = __builtin_bit_cast(bf16x8, w0);
  pa1 = __builtin_bit_cast(bf16x8, w1);
}

__global__ __launch_bounds__(128, 4) void k_attn(
    const unsigned short* __restrict__ Qf, const unsigned short* __restrict__ Kf,
    const unsigned short* __restrict__ Vf, unsigned short* __restrict__ Of) {
  const int id = blockIdx.x;                 // 0..1727
  const int xcd = id & 7, slot = id >> 3;    // slot 0..215
  const int bh = xcd * 4 + (slot / 54);      // XCD k owns bh 4k..4k+3
  const int qt = slot % 54;                  // q-tile 0..53
  const int b = bh >> 3, h = bh & 7;
  const int t = threadIdx.x, w = t >> 6, l = t & 63;
  const int lr = l & 31, hi = l >> 5;

  __shared__ float Obuf[2][32][68];
  __shared__ float Lbuf[2][32];

  const unsigned short* Qb = Qf + ((size_t)bh * 54 + qt) * 2048 + l * 8;
  bf16x8 bq[4];
#pragma unroll
  for (int kf = 0; kf < 4; ++kf) bq[kf] = *(const bf16x8*)(Qb + kf * 512);

  f32x16 oacc[2];
  oacc[0] = zero16(); oacc[1] = zero16();
  float ls = 0.f;

  const unsigned short* Kb = Kf + (size_t)bh * 54 * 2048 + l * 8;
  const unsigned short* Vb = Vf + (size_t)bh * 54 * 2048 + l * 8;

#pragma unroll 1
  for (int ck = w; ck < 54; ck += 2) {
    const unsigned short* kc = Kb + ck * 2048;
    const unsigned short* vc = Vb + ck * 2048;
    bf16x8 ak[4];
#pragma unroll
    for (int i = 0; i < 4; ++i) ak[i] = *(const bf16x8*)(kc + i * 512);

    f32x16 sA = zero16();
#pragma unroll
    for (int kf = 0; kf < 4; ++kf) sA = MFMA32(ak[kf], bq[kf], sA);

    // V issued after QK (registers reuse ak's slots; latency covered by
    // the softmax below).
    bf16x8 vb[4];
#pragma unroll
    for (int i = 0; i < 4; ++i) vb[i] = *(const bf16x8*)(vc + i * 512);

    bf16x8 pa0, pa1;
    softmax_pa(sA, ls, pa0, pa1);

    oacc[0] = MFMA32(pa0, vb[0], oacc[0]);
    oacc[0] = MFMA32(pa1, vb[1], oacc[0]);
    oacc[1] = MFMA32(pa0, vb[2], oacc[1]);
    oacc[1] = MFMA32(pa1, vb[3], oacc[1]);
  }

  // ---- epilogue: combine 2 waves via LDS, normalize, store Of
  float lt = ls + __shfl_xor(ls, 32, 64);
  if (l < 32) Lbuf[w][lr] = lt;
#pragma unroll
  for (int dt = 0; dt < 2; ++dt)
#pragma unroll
    for (int r = 0; r < 16; ++r)
      Obuf[w][(r & 3) + 8 * (r >> 2) + 4 * hi][dt * 32 + lr] = oacc[dt][r];
  __syncthreads();

  const int n = t >> 2, dq = t & 3;          // n 0..31, d-quarter 0..3
  float ltot = Lbuf[0][n] + Lbuf[1][n];
  float linv = 1.0f / ltot;
#pragma unroll
  for (int part = 0; part < 2; ++part) {
    const int d0 = dq * 16 + part * 8;
    u16x8 o8;
#pragma unroll
    for (int i = 0; i < 8; ++i) {
      float ov = Obuf[0][n][d0 + i] + Obuf[1][n][d0 + i];
      o8[i] = f2bf(ov * linv);
    }
    size_t off = (size_t)((((b * 27 + (qt >> 1)) * 16 + h * 2 + (d0 >> 5)) * 4 +
                           (qt & 1) * 2 + (n >> 4))) * 512 +
                 ((d0 >> 3) & 3) * 128 + (n & 15) * 8;
    *(u16x8*)(Of + off) = o8;
  }
}

// ---------------------------------------------------------------- out proj
// 32x32 tiles per wave: 864 blocks (72 x 12).
__global__ __launch_bounds__(256) void k_gemm_out(
    const unsigned short* __restrict__ Wf, const unsigned short* __restrict__ Of,
    const float* __restrict__ bo,
    const float* __restrict__ f0, const float* __restrict__ f1,
    const float* __restrict__ f2, float* __restrict__ out) {
  const int z = blockIdx.z, b = z / 3, f = z % 3;
  const int t = threadIdx.x, w = t >> 6, l = t & 63, lg = l >> 4, lr = l & 15;
  const int wid = blockIdx.x * 4 + w;        // 0..287
  const int mt32 = wid / 18, nt32 = wid % 18;
  const unsigned short* A = Wf + (size_t)(3 * 8 + (mt32 >> 1)) * 16 * 2048 +
                            (mt32 & 1) * 1024 + l * 8;
  const unsigned short* B = Of + (size_t)(b * 27 + f * 9 + (nt32 >> 1)) * 16 * 2048 +
                            (nt32 & 1) * 1024 + l * 8;

  f32x4 acc[2][2];
#pragma unroll
  for (int fr = 0; fr < 2; ++fr)
#pragma unroll
    for (int fc = 0; fc < 2; ++fc) acc[fr][fc] = (f32x4){0.f, 0.f, 0.f, 0.f};

#pragma unroll 2
  for (int ks = 0; ks < 16; ++ks) {
    bf16x8 af[2], bfv[2];
#pragma unroll
    for (int fr = 0; fr < 2; ++fr)
      af[fr] = *(const bf16x8*)(A + ks * 2048 + fr * 512);
#pragma unroll
    for (int fc = 0; fc < 2; ++fc)
      bfv[fc] = *(const bf16x8*)(B + ks * 2048 + fc * 512);
#pragma unroll
    for (int fr = 0; fr < 2; ++fr)
#pragma unroll
      for (int fc = 0; fc < 2; ++fc)
        acc[fr][fc] = MFMA16(af[fr], bfv[fc], acc[fr][fc]);
  }

  const float* ft = f == 0 ? f0 : f == 1 ? f1 : f2;
#pragma unroll
  for (int fr = 0; fr < 2; ++fr) {
    f32x4 b4 = *(const f32x4*)(bo + mt32 * 32 + fr * 16 + lg * 4);
#pragma unroll
    for (int fc = 0; fc < 2; ++fc) {
      int ncol = nt32 * 32 + fc * 16 + lr;
#pragma unroll
      for (int r = 0; r < 4; ++r) {
        int o = mt32 * 32 + fr * 16 + lg * 4 + r;
        out[((f * 4 + b) * 512 + o) * 576 + ncol] =
            acc[fr][fc][r] + b4[r] + ft[(b * 512 + o) * 576 + ncol];
      }
    }
  }
}

// ---------------------------------------------------------------- launcher
extern "C" void kernel_launch(void* const* d_in, const int* in_sizes, int n_in,
                              void* d_out, int out_size, void* d_ws, size_t ws_size,
                              hipStream_t stream) {
  const float* f0 = (const float*)d_in[0];
  const float* f1 = (const float*)d_in[1];
  const float* f2 = (const float*)d_in[2];
  const float* Wq = (const float*)d_in[3];
  const float* bq = (const float*)d_in[4];
  const float* Wk = (const float*)d_in[5];
  const float* bk = (const float*)d_in[6];
  const float* Wv = (const float*)d_in[7];
  const float* bv = (const float*)d_in[8];
  const float* Wo = (const float*)d_in[9];
  const float* bo = (const float*)d_in[10];
  float* out = (float*)d_out;

  char* ws = (char*)d_ws;
  unsigned short* Wf = (unsigned short*)(ws);
  unsigned short* Xf = (unsigned short*)(ws + 2097152);
  unsigned short* Qf = (unsigned short*)(ws + 9175040);
  unsigned short* Kf = (unsigned short*)(ws + 16252928);
  unsigned short* Vf = (unsigned short*)(ws + 23330816);
  unsigned short* Of = Xf;  // Xf dead after k_gemm_qkv; reused for attention out

  k_prep<<<dim3(1888), 256, 0, stream>>>(Wq, Wk, Wv, Wo, f0, f1, f2, Wf, Xf);
  k_gemm_qkv<<<dim3(2592), 256, 0, stream>>>(Wf, Xf, bq, bk, bv, Qf, Kf, Vf);
  k_attn<<<dim3(1728), 128, 0, stream>>>(Qf, Kf, Vf, Of);
  k_gemm_out<<<dim3(72, 1, 12), 256, 0, stream>>>(Wf, Of, bo, f0, f1, f2, out);
}